// Round 7
// baseline (286.087 us; speedup 1.0000x reference)
//
#include <hip/hip_runtime.h>
#include <hip/hip_fp16.h>

namespace {
constexpr int NN = 100000;   // nodes
constexpr int NE = 1600000;  // edges
constexpr int NF = 128;      // input feats
constexpr int NC = 40;       // classes (propagated dim after algebraic reorder)
constexpr int HP = 64;       // padded h row: 64 halfs = 128 B = exactly 1 L2 line
constexpr int NB = (NN + 255) / 256;      // node buckets (256 nodes each) = 391
constexpr int EPB = 4096;                 // edges per bucket-block
constexpr int EBK = (NE + EPB - 1) / EPB; // bucket blocks = 391
constexpr int CAP = 6144;                 // bucket capacity (mean 4096, sd 64 -> >16 sigma)
constexpr float FIX = 1048576.0f;         // 2^20 fixed-point scale for deg
constexpr int NPB = 51;                   // nodes per hop block (51*5 = 255 threads)
constexpr int HB  = (NN + NPB - 1) / NPB; // hop blocks = 1961
constexpr int TS  = 2048;                 // staged pairs per tile (16 KB LDS)
}

struct alignas(16) H8 { __half2 a, b, c, d; };   // 8 halfs = one b128

__device__ inline __half2 f2h2(float x, float y) {
    return __halves2half2(__float2half_rn(x), __float2half_rn(y));
}

// ---------------------------------------------------------------------------
// K1 (fused): blocks [0,EBK) = coarse bucket sort of edges by col>>8; blocks
// [EBK,EBK+NB) = the XW GEMM writing UNSCALED g0[n] = fp16(x[n]@W).
// ROUND-7 CHANGE: bstage scatter uses NONTEMPORAL u64 stores — round-6
// counters showed WRITE_SIZE 51 MB vs 25.6 architectural (one 32B sector +
// RFO per 8B scattered record); nt skips the write-allocate, the round-0
// k_scatter trick.
__global__ __launch_bounds__(256) void k_fused(const int* __restrict__ col,
                                               const int* __restrict__ row,
                                               const float* __restrict__ w,
                                               unsigned int* __restrict__ cursor,
                                               int2* __restrict__ bstage,
                                               const float* __restrict__ x,
                                               const float* __restrict__ W,
                                               __half* __restrict__ g0) {
    __shared__ char sb[20480];            // union: bucket 4.7 KB | GEMM lW 20 KB
    int t = threadIdx.x;
    if (blockIdx.x < (unsigned)EBK) {
        unsigned int* lhist = (unsigned int*)sb;
        unsigned int* lbase = lhist + NB;
        unsigned int* lrank = lbase + NB;
        for (int i = t; i < NB; i += 256) { lhist[i] = 0u; lrank[i] = 0u; }
        __syncthreads();
        int e0 = blockIdx.x * EPB;
        int e1 = min(e0 + EPB, NE);
        for (int e = e0 + t; e < e1; e += 256)
            atomicAdd(&lhist[col[e] >> 8], 1u);
        __syncthreads();
        for (int i = t; i < NB; i += 256) {
            unsigned c = lhist[i];
            lbase[i] = c ? atomicAdd(&cursor[i], c) : 0u;
        }
        __syncthreads();
        for (int e = e0 + t; e < e1; e += 256) {
            int c = col[e];                  // L1-hot re-read
            int b = c >> 8;
            unsigned r = atomicAdd(&lrank[b], 1u);
            unsigned long long u =
                (unsigned long long)(unsigned)((row[e] & 0x1FFFF) | ((c & 255) << 17)) |
                ((unsigned long long)(unsigned)__float_as_int(w[e]) << 32);
            __builtin_nontemporal_store(
                u, (unsigned long long*)(bstage + (size_t)b * CAP + lbase[b] + r));
        }
    } else {
        float4* lW = (float4*)sb;            // 1280 float4 = 20 KB, row k = 10 float4
        {   // stage W: 5 coalesced float4 loads/thread
            const float4* Wg = (const float4*)W;
#pragma unroll
            for (int i = 0; i < 5; ++i) lW[t + i * 256] = Wg[t + i * 256];
        }
        __syncthreads();
        int n = (blockIdx.x - EBK) * 256 + t;
        if (n >= NN) return;
        const float4* xr = (const float4*)(x + (size_t)n * NF);  // 32 float4
        float acc[NC];
#pragma unroll
        for (int j = 0; j < NC; ++j) acc[j] = 0.f;
        for (int k4 = 0; k4 < NF / 4; ++k4) {
            float4 xv = xr[k4];
#pragma unroll
            for (int kk = 0; kk < 4; ++kk) {
                float xk = (kk == 0) ? xv.x : (kk == 1) ? xv.y : (kk == 2) ? xv.z : xv.w;
                int k = k4 * 4 + kk;
#pragma unroll
                for (int j4 = 0; j4 < 10; ++j4) {
                    float4 wv = lW[k * 10 + j4];   // LDS broadcast
                    acc[j4 * 4 + 0] += xk * wv.x;
                    acc[j4 * 4 + 1] += xk * wv.y;
                    acc[j4 * 4 + 2] += xk * wv.z;
                    acc[j4 * 4 + 3] += xk * wv.w;
                }
            }
        }
        H8* o = (H8*)(g0 + (size_t)n * HP);
#pragma unroll
        for (int g = 0; g < 5; ++g) {         // 5 x 8 halfs = 40 (UNSCALED g0)
            H8 v;
            v.a = f2h2(acc[g * 8 + 0], acc[g * 8 + 1]);
            v.b = f2h2(acc[g * 8 + 2], acc[g * 8 + 3]);
            v.c = f2h2(acc[g * 8 + 4], acc[g * 8 + 5]);
            v.d = f2h2(acc[g * 8 + 6], acc[g * 8 + 7]);
            o[g] = v;
        }
    }
}

// K2: exclusive scan of 391 bucket counts -> bbase[0..NB]; offs[NN] = NE.
__global__ __launch_bounds__(512) void k_bscan(const unsigned int* __restrict__ cursor,
                                               int* __restrict__ bbase,
                                               int* __restrict__ offs) {
    __shared__ int s[512];
    int t = threadIdx.x;
    int v = (t < NB) ? (int)cursor[t] : 0;
    s[t] = v;
    __syncthreads();
    for (int off = 1; off < 512; off <<= 1) {
        int add = (t >= off) ? s[t - off] : 0;
        __syncthreads();
        s[t] += add;
        __syncthreads();
    }
    if (t < NB) bbase[t] = s[t] - v;          // exclusive
    if (t == NB) bbase[NB] = s[NB - 1];       // total = NE
    if (t == 0)  offs[NN] = NE;
}

// K3 (sort only), ROUND-7 RESTRUCTURE for the serial-phase/occupancy problem
// (391 blocks x 4 waves = 6 waves/CU, bstage read TWICE, 1.6M pass-2 LDS
// atomics):
//  - 512 threads/block (8 waves): every barrier-separated phase runs 2x wider;
//  - pass 1 stages the bucket's records in LDS (48 KB, CAP-sized) so bstage
//    is read ONCE (nontemporal — single use);
//  - the pass-1 deg atomic is RETURNING: its count field is the edge's
//    in-bin rank (u8 LDS), so pass 2 has NO atomics at all.
// Deg is an integer fixed-point sum -> order-independent, bit-identical.
// Pair order within a node's segment may permute (hop fp32 add order only).
__global__ __launch_bounds__(512) void k_sort(const int2* __restrict__ bstage,
                                              const int* __restrict__ bbase,
                                              int* __restrict__ offs,
                                              float* __restrict__ invdis,
                                              int2* __restrict__ pair,
                                              __half* __restrict__ g0) {
    __shared__ int2 rec[CAP];                 // 48 KB staged records
    __shared__ unsigned char rk8[CAP];        // 6 KB in-bin ranks (max in-deg ~45)
    __shared__ unsigned long long lpk[256];   // [63:40]=cnt, [39:0]=deg fixed-point
    __shared__ int ls[256];                   // counts -> scan -> starts
    __shared__ float ldis[256];
    int t = threadIdx.x;
    int b = blockIdx.x;
    int base = bbase[b];
    int cnt  = bbase[b + 1] - base;
    if (t < 256) lpk[t] = 0ull;
    __syncthreads();
    const unsigned long long* bs64 = (const unsigned long long*)(bstage + (size_t)b * CAP);
    for (int j = t; j < cnt; j += 512) {
        unsigned long long u = __builtin_nontemporal_load(bs64 + j);
        int2 s; s.x = (int)(unsigned)u; s.y = (int)(u >> 32);
        rec[j] = s;
        int cl = (s.x >> 17) & 255;
        unsigned long long q =
            (unsigned long long)(unsigned)(__int_as_float(s.y) * FIX + 0.5f);
        unsigned long long old = atomicAdd(&lpk[cl], (1ull << 40) | q);
        rk8[j] = (unsigned char)(old >> 40);  // rank within bin, free
    }
    __syncthreads();
    if (t < 256) {
        int myc = (int)(lpk[t] >> 40);
        float deg = (float)(lpk[t] & ((1ull << 40) - 1)) * (1.0f / FIX);
        float dis = (deg > 0.f) ? rsqrtf(deg) : 0.f;
        ldis[t] = dis;
        ls[t] = myc;
        int n = b * 256 + t;
        if (n < NN) {
            invdis[n] = sqrtf(fmaxf(deg, 0.f));   // = 1/dis (0 when deg==0)
            *(float*)(g0 + (size_t)n * HP + 40) = dis;   // byte 80 of the h row
        }
    }
    __syncthreads();
    for (int off = 1; off < 256; off <<= 1) {
        int add = (t < 256 && t >= off) ? ls[t - off] : 0;
        __syncthreads();
        if (t < 256) ls[t] += add;
        __syncthreads();
    }
    if (t < 256) {
        int myc = (int)(lpk[t] >> 40);
        ls[t] -= myc;                         // exclusive start within bucket
        int n = b * 256 + t;
        if (n < NN) offs[n] = base + ls[t];
    }
    __syncthreads();
    for (int j = t; j < cnt; j += 512) {
        int2 s = rec[j];                      // LDS (no global re-read)
        int cl = (s.x >> 17) & 255;
        float d = ldis[cl];
        int2 v;
        v.x = s.x & 0x1FFFF;
        v.y = __float_as_int(__int_as_float(s.y) * d * d);   // w * dis[c]^2
        pair[base + ls[cl] + rk8[j]] = v;     // atomic-free, semi-coalesced
    }
}

// LDS-staged pull hop. Block = 51 nodes x 5 threads (255 active).
// WD (hop 1 only): weight = pair.y * dis_row, dis_row read from byte 80 of
// the gathered row's own 128B line (L1-hot). Hops 2..3: weight = pair.y.
// FINAL: multiply by invdis[n] (h3 = D A z2) and store fp32.
template <bool FINAL, bool WD>
__global__ __launch_bounds__(256) void k_hop(const int* __restrict__ offs,
                                             const int2* __restrict__ pair,
                                             const __half* __restrict__ hin,
                                             __half* __restrict__ houth,
                                             float* __restrict__ houtf,
                                             const float* __restrict__ invdis) {
    __shared__ int2 tile[TS];
    __shared__ int erange[2];
    int t = threadIdx.x;
    int g = t / 5;                      // local node 0..50
    int n = blockIdx.x * NPB + g;
    bool active = (t < NPB * 5) && (n < NN);
    int vo = (t - g * 5) * 8;           // half offset 0,8,16,24,32
    int s0 = 0, s1 = 0;
    if (active) {
        s0 = offs[n];
        s1 = offs[n + 1];               // offs[NN] = NE
    }
    if (t == 0) {
        int n0 = blockIdx.x * NPB;
        int nl = min(n0 + NPB, NN);
        erange[0] = offs[n0];
        erange[1] = offs[nl];
    }
    __syncthreads();
    int E0 = erange[0], E1 = erange[1];
    float acc[8];
#pragma unroll
    for (int j = 0; j < 8; ++j) acc[j] = 0.f;
    int i = s0;
#define ACC8(m, wgt) { float2 f_;                                        \
    f_ = __half22float2((m).a); acc[0] += f_.x * (wgt); acc[1] += f_.y * (wgt); \
    f_ = __half22float2((m).b); acc[2] += f_.x * (wgt); acc[3] += f_.y * (wgt); \
    f_ = __half22float2((m).c); acc[4] += f_.x * (wgt); acc[5] += f_.y * (wgt); \
    f_ = __half22float2((m).d); acc[6] += f_.x * (wgt); acc[7] += f_.y * (wgt); }
    for (int t0 = E0; t0 < E1; t0 += TS) {
        int lim = min(t0 + TS, E1);
        int cnt = lim - t0;
        for (int j = t; j < cnt; j += 256) tile[j] = pair[t0 + j];  // coalesced
        __syncthreads();
        if (active) {
            int hi = min(s1, lim);
            for (; i + 4 <= hi; i += 4) {
                int2 p0 = tile[i - t0];
                int2 p1 = tile[i + 1 - t0];
                int2 p2 = tile[i + 2 - t0];
                int2 p3 = tile[i + 3 - t0];
                const __half* r0 = hin + (size_t)p0.x * HP;
                const __half* r1 = hin + (size_t)p1.x * HP;
                const __half* r2 = hin + (size_t)p2.x * HP;
                const __half* r3 = hin + (size_t)p3.x * HP;
                H8 m0 = *(const H8*)(r0 + vo);
                H8 m1 = *(const H8*)(r1 + vo);
                H8 m2 = *(const H8*)(r2 + vo);
                H8 m3 = *(const H8*)(r3 + vo);
                float w0 = __int_as_float(p0.y);
                float w1 = __int_as_float(p1.y);
                float w2 = __int_as_float(p2.y);
                float w3 = __int_as_float(p3.y);
                if (WD) {                     // dis_row from the same 128B line
                    w0 *= *(const float*)(r0 + 40);
                    w1 *= *(const float*)(r1 + 40);
                    w2 *= *(const float*)(r2 + 40);
                    w3 *= *(const float*)(r3 + 40);
                }
                ACC8(m0, w0) ACC8(m1, w1) ACC8(m2, w2) ACC8(m3, w3)
            }
            for (; i < hi; ++i) {
                int2 p0 = tile[i - t0];
                const __half* r0 = hin + (size_t)p0.x * HP;
                H8 m0 = *(const H8*)(r0 + vo);
                float w0 = __int_as_float(p0.y);
                if (WD) w0 *= *(const float*)(r0 + 40);
                ACC8(m0, w0)
            }
        }
        __syncthreads();
    }
#undef ACC8
    if (active) {
        if (FINAL) {
            float sc = invdis[n];
            float* o = houtf + (size_t)n * NC + vo;
            float4 v0 = {acc[0] * sc, acc[1] * sc, acc[2] * sc, acc[3] * sc};
            float4 v1 = {acc[4] * sc, acc[5] * sc, acc[6] * sc, acc[7] * sc};
            *(float4*)(o) = v0;
            *(float4*)(o + 4) = v1;
        } else {
            H8 v;
            v.a = f2h2(acc[0], acc[1]);
            v.b = f2h2(acc[2], acc[3]);
            v.c = f2h2(acc[4], acc[5]);
            v.d = f2h2(acc[6], acc[7]);
            *(H8*)(houth + (size_t)n * HP + vo) = v;
        }
    }
}

extern "C" void kernel_launch(void* const* d_in, const int* in_sizes, int n_in,
                              void* d_out, int out_size, void* d_ws, size_t ws_size,
                              hipStream_t stream) {
    const float* x  = (const float*)d_in[0];
    const int*   ei = (const int*)d_in[1];   // [2, NE]
    const float* w  = (const float*)d_in[2];
    const float* W  = (const float*)d_in[3]; // [128, 40]
    const int* row = ei;
    const int* col = ei + NE;
    float* out = (float*)d_out;              // [NN, NC] fp32, written by hop3 only

    // workspace (~45.6 MB):
    //   [0, 19.2)   bstage  (dead after k_sort)  -- hb OVERLAYS [0, 12.8)
    //   [19.2,32.0) ha  (g0/z0 with dis at row byte 80; later z2)
    //   [32.0,44.8) pair {row, w*dis^2}
    //   then offs[NN+1], bbase[NB+1], invdis[NN], cursor[NB]
    char* base = (char*)d_ws;
    int2* bstage = (int2*)base;
    __half* hb   = (__half*)base;                         // born at hop1
    char* p = base + (size_t)NB * CAP * 8;
    __half* ha = (__half*)p;        p += (size_t)NN * HP * 2;
    int2* pair = (int2*)p;          p += (size_t)NE * 8;
    int*  offs = (int*)p;           p += (size_t)(NN + 1) * 4;
    int*  bbase = (int*)p;          p += (size_t)(NB + 1) * 4;
    float* invdis = (float*)p;      p += (size_t)NN * 4;
    unsigned int* cursor = (unsigned int*)p;

    hipMemsetAsync(cursor, 0, (size_t)NB * 4, stream);
    k_fused<<<EBK + NB, 256, 0, stream>>>(col, row, w, cursor, bstage, x, W, ha);
    k_bscan<<<1, 512, 0, stream>>>(cursor, bbase, offs);
    k_sort<<<NB, 512, 0, stream>>>(bstage, bbase, offs, invdis, pair, ha);

    k_hop<false, true ><<<HB, 256, 0, stream>>>(offs, pair, ha, hb, nullptr, nullptr); // z1
    k_hop<false, false><<<HB, 256, 0, stream>>>(offs, pair, hb, ha, nullptr, nullptr); // z2
    k_hop<true,  false><<<HB, 256, 0, stream>>>(offs, pair, ha, nullptr, out, invdis); // h3
}

// Round 8
// 271.279 us; speedup vs baseline: 1.0546x; 1.0546x over previous
//
#include <hip/hip_runtime.h>
#include <hip/hip_fp16.h>

namespace {
constexpr int NN = 100000;   // nodes
constexpr int NE = 1600000;  // edges
constexpr int NF = 128;      // input feats
constexpr int NC = 40;       // classes (propagated dim after algebraic reorder)
constexpr int HP = 64;       // padded h row: 64 halfs = 128 B = exactly 1 L2 line
constexpr int NB = (NN + 255) / 256;      // node buckets (256 nodes each) = 391
constexpr int EPB = 4096;                 // edges per bucket-block
constexpr int EBK = (NE + EPB - 1) / EPB; // bucket blocks = 391
constexpr int CAP = 6144;                 // bucket capacity (mean 4096, sd 64 -> >16 sigma)
constexpr float FIX = 1048576.0f;         // 2^20 fixed-point scale for deg
constexpr int NPB = 51;                   // nodes per hop block (51*5 = 255 threads)
constexpr int HB  = (NN + NPB - 1) / NPB; // hop blocks = 1961
constexpr int TS  = 2048;                 // staged pairs per tile (16 KB LDS)
}

struct alignas(16) H8 { __half2 a, b, c, d; };   // 8 halfs = one b128

__device__ inline __half2 f2h2(float x, float y) {
    return __halves2half2(__float2half_rn(x), __float2half_rn(y));
}

// ---------------------------------------------------------------------------
// K1: coarse bucket sort of edges by col>>8 (391 bins of 256 nodes).
// Round-1 proven form, NORMAL stores. [round-7 post-mortem: nt-store on the
// bstage scatter REGRESSED (WRITE 51->60 MB, k_fused 78->91 us): bin runs of
// ~10 consecutive 8B records were already L2-write-combined; nt bypassed L2
// and paid one 32B memory-side sector per record. nt only helps fully-random
// single-record-per-line scatters (round-0 k_scatter).]
// Also split from the GEMM again: round-4 (split, 264us) vs round-6 (fused,
// 267us) shows fusion pays nothing on a serialized stream, and the 78us
// fused kernel kept the ~55us hops out of rocprof's top-5.
__global__ __launch_bounds__(256) void k_bucket(const int* __restrict__ col,
                                                const int* __restrict__ row,
                                                const float* __restrict__ w,
                                                unsigned int* __restrict__ cursor,
                                                int2* __restrict__ bstage) {
    __shared__ unsigned int lhist[NB];
    __shared__ unsigned int lbase[NB];
    __shared__ unsigned int lrank[NB];
    int t = threadIdx.x;
    for (int i = t; i < NB; i += 256) { lhist[i] = 0u; lrank[i] = 0u; }
    __syncthreads();
    int e0 = blockIdx.x * EPB;
    int e1 = min(e0 + EPB, NE);
    for (int e = e0 + t; e < e1; e += 256)
        atomicAdd(&lhist[col[e] >> 8], 1u);
    __syncthreads();
    for (int i = t; i < NB; i += 256) {
        unsigned c = lhist[i];
        lbase[i] = c ? atomicAdd(&cursor[i], c) : 0u;
    }
    __syncthreads();
    for (int e = e0 + t; e < e1; e += 256) {
        int c = col[e];                  // L1-hot re-read
        int b = c >> 8;
        unsigned r = atomicAdd(&lrank[b], 1u);
        int2 v;
        v.x = (row[e] & 0x1FFFF) | ((c & 255) << 17);
        v.y = __float_as_int(w[e]);
        bstage[(size_t)b * CAP + lbase[b] + r] = v;
    }
}

// K2: exclusive scan of 391 bucket counts -> bbase[0..NB]; offs[NN] = NE.
__global__ __launch_bounds__(512) void k_bscan(const unsigned int* __restrict__ cursor,
                                               int* __restrict__ bbase,
                                               int* __restrict__ offs) {
    __shared__ int s[512];
    int t = threadIdx.x;
    int v = (t < NB) ? (int)cursor[t] : 0;
    s[t] = v;
    __syncthreads();
    for (int off = 1; off < 512; off <<= 1) {
        int add = (t >= off) ? s[t - off] : 0;
        __syncthreads();
        s[t] += add;
        __syncthreads();
    }
    if (t < NB) bbase[t] = s[t] - v;          // exclusive
    if (t == NB) bbase[NB] = s[NB - 1];       // total = NE
    if (t == 0)  offs[NN] = NE;
}

// K3 (sort): round-7 restructure, kept — 512 threads (8 waves, 2x wider
// barrier phases), bstage read ONCE via nt LOAD into 48KB LDS staging,
// returning-rank pass-1 atomic (u8 ranks) so pass 2 is atomic-free.
// Writes dis[NN] (fp32) for k_gemm's fold instead of depositing into g0
// rows — hops no longer need the per-edge dis multiply at all.
__global__ __launch_bounds__(512) void k_sort(const int2* __restrict__ bstage,
                                              const int* __restrict__ bbase,
                                              int* __restrict__ offs,
                                              float* __restrict__ invdis,
                                              float* __restrict__ dis_g,
                                              int2* __restrict__ pair) {
    __shared__ int2 rec[CAP];                 // 48 KB staged records
    __shared__ unsigned char rk8[CAP];        // 6 KB in-bin ranks (max in-deg ~45)
    __shared__ unsigned long long lpk[256];   // [63:40]=cnt, [39:0]=deg fixed-point
    __shared__ int ls[256];                   // counts -> scan -> starts
    __shared__ float ldis[256];
    int t = threadIdx.x;
    int b = blockIdx.x;
    int base = bbase[b];
    int cnt  = bbase[b + 1] - base;
    if (t < 256) lpk[t] = 0ull;
    __syncthreads();
    const unsigned long long* bs64 = (const unsigned long long*)(bstage + (size_t)b * CAP);
    for (int j = t; j < cnt; j += 512) {
        unsigned long long u = __builtin_nontemporal_load(bs64 + j);
        int2 s; s.x = (int)(unsigned)u; s.y = (int)(u >> 32);
        rec[j] = s;
        int cl = (s.x >> 17) & 255;
        unsigned long long q =
            (unsigned long long)(unsigned)(__int_as_float(s.y) * FIX + 0.5f);
        unsigned long long old = atomicAdd(&lpk[cl], (1ull << 40) | q);
        rk8[j] = (unsigned char)(old >> 40);  // rank within bin, free
    }
    __syncthreads();
    if (t < 256) {
        int myc = (int)(lpk[t] >> 40);
        float deg = (float)(lpk[t] & ((1ull << 40) - 1)) * (1.0f / FIX);
        float dis = (deg > 0.f) ? rsqrtf(deg) : 0.f;
        ldis[t] = dis;
        ls[t] = myc;
        int n = b * 256 + t;
        if (n < NN) {
            invdis[n] = sqrtf(fmaxf(deg, 0.f));   // = 1/dis (0 when deg==0)
            dis_g[n]  = dis;                      // for k_gemm's z0 fold
        }
    }
    __syncthreads();
    for (int off = 1; off < 256; off <<= 1) {
        int add = (t < 256 && t >= off) ? ls[t - off] : 0;
        __syncthreads();
        if (t < 256) ls[t] += add;
        __syncthreads();
    }
    if (t < 256) {
        int myc = (int)(lpk[t] >> 40);
        ls[t] -= myc;                         // exclusive start within bucket
        int n = b * 256 + t;
        if (n < NN) offs[n] = base + ls[t];
    }
    __syncthreads();
    for (int j = t; j < cnt; j += 512) {
        int2 s = rec[j];                      // LDS (no global re-read)
        int cl = (s.x >> 17) & 255;
        float d = ldis[cl];
        int2 v;
        v.x = s.x & 0x1FFFF;
        v.y = __float_as_int(__int_as_float(s.y) * d * d);   // w * dis[c]^2
        pair[base + ls[cl] + rk8[j]] = v;     // atomic-free, semi-coalesced
    }
}

// K4 (GEMM): z0[n] = fp16(dis[n] * (x[n] @ W)) — single fp16 rounding, same
// numerics as the measured-good round-4 kernel. W staged in LDS (20 KB,
// broadcast ds_read); dis from the coalesced dis_g array written by k_sort.
__global__ __launch_bounds__(256) void k_gemm(const float* __restrict__ x,
                                              const float* __restrict__ W,
                                              const float* __restrict__ dis_g,
                                              __half* __restrict__ z0) {
    __shared__ float4 lW[NF * NC / 4];        // 1280 float4 = 20 KB, row k = 10 float4
    int t = threadIdx.x;
    {   // stage W: 5 coalesced float4 loads/thread
        const float4* Wg = (const float4*)W;
#pragma unroll
        for (int i = 0; i < 5; ++i) lW[t + i * 256] = Wg[t + i * 256];
    }
    __syncthreads();
    int n = blockIdx.x * 256 + t;
    if (n >= NN) return;
    const float4* xr = (const float4*)(x + (size_t)n * NF);  // 32 float4
    float acc[NC];
#pragma unroll
    for (int j = 0; j < NC; ++j) acc[j] = 0.f;
    for (int k4 = 0; k4 < NF / 4; ++k4) {
        float4 xv = xr[k4];
#pragma unroll
        for (int kk = 0; kk < 4; ++kk) {
            float xk = (kk == 0) ? xv.x : (kk == 1) ? xv.y : (kk == 2) ? xv.z : xv.w;
            int k = k4 * 4 + kk;
#pragma unroll
            for (int j4 = 0; j4 < 10; ++j4) {
                float4 wv = lW[k * 10 + j4];   // LDS broadcast
                acc[j4 * 4 + 0] += xk * wv.x;
                acc[j4 * 4 + 1] += xk * wv.y;
                acc[j4 * 4 + 2] += xk * wv.z;
                acc[j4 * 4 + 3] += xk * wv.w;
            }
        }
    }
    float sc = dis_g[n];                      // fold dis (one fp16 round total)
    H8* o = (H8*)(z0 + (size_t)n * HP);
#pragma unroll
    for (int g = 0; g < 5; ++g) {             // 5 x 8 halfs = 40
        H8 v;
        v.a = f2h2(acc[g * 8 + 0] * sc, acc[g * 8 + 1] * sc);
        v.b = f2h2(acc[g * 8 + 2] * sc, acc[g * 8 + 3] * sc);
        v.c = f2h2(acc[g * 8 + 4] * sc, acc[g * 8 + 5] * sc);
        v.d = f2h2(acc[g * 8 + 6] * sc, acc[g * 8 + 7] * sc);
        o[g] = v;
    }
}

// LDS-staged pull hop. Block = 51 nodes x 5 threads (255 active). All hops
// identical now (weight = pair.y = w*dis[c]^2; z0 pre-scaled by dis).
// FINAL: multiply by invdis[n] (h3 = D A z2) and store fp32.
template <bool FINAL>
__global__ __launch_bounds__(256) void k_hop(const int* __restrict__ offs,
                                             const int2* __restrict__ pair,
                                             const __half* __restrict__ hin,
                                             __half* __restrict__ houth,
                                             float* __restrict__ houtf,
                                             const float* __restrict__ invdis) {
    __shared__ int2 tile[TS];
    __shared__ int erange[2];
    int t = threadIdx.x;
    int g = t / 5;                      // local node 0..50
    int n = blockIdx.x * NPB + g;
    bool active = (t < NPB * 5) && (n < NN);
    int vo = (t - g * 5) * 8;           // half offset 0,8,16,24,32
    int s0 = 0, s1 = 0;
    if (active) {
        s0 = offs[n];
        s1 = offs[n + 1];               // offs[NN] = NE
    }
    if (t == 0) {
        int n0 = blockIdx.x * NPB;
        int nl = min(n0 + NPB, NN);
        erange[0] = offs[n0];
        erange[1] = offs[nl];
    }
    __syncthreads();
    int E0 = erange[0], E1 = erange[1];
    float acc[8];
#pragma unroll
    for (int j = 0; j < 8; ++j) acc[j] = 0.f;
    int i = s0;
#define ACC8(m, wgt) { float2 f_;                                        \
    f_ = __half22float2((m).a); acc[0] += f_.x * (wgt); acc[1] += f_.y * (wgt); \
    f_ = __half22float2((m).b); acc[2] += f_.x * (wgt); acc[3] += f_.y * (wgt); \
    f_ = __half22float2((m).c); acc[4] += f_.x * (wgt); acc[5] += f_.y * (wgt); \
    f_ = __half22float2((m).d); acc[6] += f_.x * (wgt); acc[7] += f_.y * (wgt); }
    for (int t0 = E0; t0 < E1; t0 += TS) {
        int lim = min(t0 + TS, E1);
        int cnt = lim - t0;
        for (int j = t; j < cnt; j += 256) tile[j] = pair[t0 + j];  // coalesced
        __syncthreads();
        if (active) {
            int hi = min(s1, lim);
            for (; i + 4 <= hi; i += 4) {
                int2 p0 = tile[i - t0];
                int2 p1 = tile[i + 1 - t0];
                int2 p2 = tile[i + 2 - t0];
                int2 p3 = tile[i + 3 - t0];
                H8 m0 = *(const H8*)(hin + (size_t)p0.x * HP + vo);
                H8 m1 = *(const H8*)(hin + (size_t)p1.x * HP + vo);
                H8 m2 = *(const H8*)(hin + (size_t)p2.x * HP + vo);
                H8 m3 = *(const H8*)(hin + (size_t)p3.x * HP + vo);
                float w0 = __int_as_float(p0.y);
                float w1 = __int_as_float(p1.y);
                float w2 = __int_as_float(p2.y);
                float w3 = __int_as_float(p3.y);
                ACC8(m0, w0) ACC8(m1, w1) ACC8(m2, w2) ACC8(m3, w3)
            }
            for (; i < hi; ++i) {
                int2 p0 = tile[i - t0];
                H8 m0 = *(const H8*)(hin + (size_t)p0.x * HP + vo);
                float w0 = __int_as_float(p0.y);
                ACC8(m0, w0)
            }
        }
        __syncthreads();
    }
#undef ACC8
    if (active) {
        if (FINAL) {
            float sc = invdis[n];
            float* o = houtf + (size_t)n * NC + vo;
            float4 v0 = {acc[0] * sc, acc[1] * sc, acc[2] * sc, acc[3] * sc};
            float4 v1 = {acc[4] * sc, acc[5] * sc, acc[6] * sc, acc[7] * sc};
            *(float4*)(o) = v0;
            *(float4*)(o + 4) = v1;
        } else {
            H8 v;
            v.a = f2h2(acc[0], acc[1]);
            v.b = f2h2(acc[2], acc[3]);
            v.c = f2h2(acc[4], acc[5]);
            v.d = f2h2(acc[6], acc[7]);
            *(H8*)(houth + (size_t)n * HP + vo) = v;
        }
    }
}

extern "C" void kernel_launch(void* const* d_in, const int* in_sizes, int n_in,
                              void* d_out, int out_size, void* d_ws, size_t ws_size,
                              hipStream_t stream) {
    const float* x  = (const float*)d_in[0];
    const int*   ei = (const int*)d_in[1];   // [2, NE]
    const float* w  = (const float*)d_in[2];
    const float* W  = (const float*)d_in[3]; // [128, 40]
    const int* row = ei;
    const int* col = ei + NE;
    float* out = (float*)d_out;              // [NN, NC] fp32, written by hop3 only

    // workspace (~46 MB):
    //   [0, 19.2)   bstage  (dead after k_sort)  -- hb OVERLAYS [0, 12.8)
    //   [19.2,32.0) ha  (z0; later z2)
    //   [32.0,44.8) pair {row, w*dis^2}
    //   then offs[NN+1], bbase[NB+1], invdis[NN], dis[NN], cursor[NB]
    char* base = (char*)d_ws;
    int2* bstage = (int2*)base;
    __half* hb   = (__half*)base;                         // born at hop1
    char* p = base + (size_t)NB * CAP * 8;
    __half* ha = (__half*)p;        p += (size_t)NN * HP * 2;
    int2* pair = (int2*)p;          p += (size_t)NE * 8;
    int*  offs = (int*)p;           p += (size_t)(NN + 1) * 4;
    int*  bbase = (int*)p;          p += (size_t)(NB + 1) * 4;
    float* invdis = (float*)p;      p += (size_t)NN * 4;
    float* dis_g = (float*)p;       p += (size_t)NN * 4;
    unsigned int* cursor = (unsigned int*)p;

    hipMemsetAsync(cursor, 0, (size_t)NB * 4, stream);
    k_bucket<<<EBK, 256, 0, stream>>>(col, row, w, cursor, bstage);
    k_bscan<<<1, 512, 0, stream>>>(cursor, bbase, offs);
    k_sort<<<NB, 512, 0, stream>>>(bstage, bbase, offs, invdis, dis_g, pair);
    k_gemm<<<NB, 256, 0, stream>>>(x, W, dis_g, ha);

    k_hop<false><<<HB, 256, 0, stream>>>(offs, pair, ha, hb, nullptr, nullptr); // z1
    k_hop<false><<<HB, 256, 0, stream>>>(offs, pair, hb, ha, nullptr, nullptr); // z2
    k_hop<true ><<<HB, 256, 0, stream>>>(offs, pair, ha, nullptr, out, invdis); // h3
}